// Round 7
// baseline (338.884 us; speedup 1.0000x reference)
//
#include <hip/hip_runtime.h>
#include <hip/hip_bf16.h>

// Problem constants
#define V_   16000
#define D_   1024
#define H_   1024
#define E_   8
#define C_   16
#define B_   64
#define S_   512
#define GH_  256
#define NPAIR 128   // B_ * K(=2)

typedef short  bf16x8 __attribute__((ext_vector_type(8)));
typedef ushort u16x8  __attribute__((ext_vector_type(8)));
typedef float  f32x4  __attribute__((ext_vector_type(4)));

static __device__ __forceinline__ ushort f2bf(float f) {
  union { float f; unsigned u; } un; un.f = f;
  unsigned u = un.u;
  return (ushort)((u + 0x7FFFu + ((u >> 16) & 1u)) >> 16);  // RNE
}

static __device__ __forceinline__ unsigned pk2(float lo, float hi) {
  __hip_bfloat162 h = __float22bfloat162_rn(make_float2(lo, hi));  // v_cvt_pk_bf16_f32
  unsigned r; __builtin_memcpy(&r, &h, sizeof(r)); return r;
}

static __device__ __forceinline__ uint4 cvt8(f32x4 a, f32x4 b) {
  uint4 w;
  w.x = pk2(a[0], a[1]); w.y = pk2(a[2], a[3]);
  w.z = pk2(b[0], b[1]); w.w = pk2(b[2], b[3]);
  return w;
}

static __device__ __forceinline__ void gload_lds16(const void* g, void* l) {
  __builtin_amdgcn_global_load_lds((const __attribute__((address_space(1))) void*)g,
                                   (__attribute__((address_space(3))) void*)l, 16, 0, 0);
}

// ---------------------------------------------------------------------------
// Kernel 0 (fused prep):
//  blocks [0,2048): repack exp_w1 (E,D,H) f32 -> w1t bf16 as 64-KiB "chunks":
//   chunk ci = kkpair*2 + hh covers k in [kkpair*64,+64), h in [hh*512,+512).
//   Within chunk: frag f = wid*8 + ks*4 + fi (1 KiB = 64 lanes x 16B) holds
//   A[h = hh*512 + wid*64 + fi*16 + (lane&15)][k = kkpair*64 + ks*32 + (lane>>4)*8 + j]
//   -> expert kernel DMA copies chunks linearly into LDS; reads are
//      conflict-free lane*16 ds_read_b128.
//  blocks [2048,2560): partial pooling partial[b][sb][d]
__global__ void prep_kernel(const float* __restrict__ w1, ushort* __restrict__ w1t,
                            const int* __restrict__ x, const float* __restrict__ emb,
                            float* __restrict__ partial) {
  __shared__ float tile[64][65];
  const int id = blockIdx.x;
  if (id < 2048) {
    const int e = id >> 8, rem = id & 255;
    const int dtile = rem & 15, htile = rem >> 4;
    const int d0 = dtile * 64, h0 = htile * 64;
    const float* src = w1 + (size_t)e * D_ * H_;
    for (int i = threadIdx.x; i < 64 * 64; i += 256) {
      int r = i >> 6, c = i & 63;                 // r: d-local (k), c: h-local
      tile[r][c] = src[(size_t)(d0 + r) * H_ + h0 + c];
    }
    __syncthreads();
    for (int i = threadIdx.x; i < 512; i += 256) {
      int chunk = i >> 6, lane = i & 63;
      int kkl = chunk >> 2, htl = chunk & 3;      // ks, fi
      int l15 = lane & 15, l16 = lane >> 4;
      u16x8 v;
      #pragma unroll
      for (int j = 0; j < 8; ++j)
        v[j] = f2bf(tile[kkl * 32 + l16 * 8 + j][htl * 16 + l15]);
      int ci = dtile * 2 + (htile >> 3);
      int f  = (htile & 7) * 8 + kkl * 4 + htl;
      size_t off = ((size_t)(e * 32 + ci)) * 32768 + f * 512 + lane * 8;
      *reinterpret_cast<u16x8*>(w1t + off) = v;
    }
  } else {
    const int pid = id - 2048;
    const int b = pid >> 3, sb = pid & 7, t = threadIdx.x;
    const int* xr = x + b * S_ + sb * 64;
    float4 acc = make_float4(0.f, 0.f, 0.f, 0.f);
    #pragma unroll 4
    for (int s = 0; s < 64; ++s) {
      const float4* row = reinterpret_cast<const float4*>(emb + (size_t)xr[s] * D_);
      float4 v = row[t];
      acc.x += v.x; acc.y += v.y; acc.z += v.z; acc.w += v.w;
    }
    reinterpret_cast<float4*>(partial + ((size_t)b * 8 + sb) * D_)[t] = acc;
  }
}

// ---------------------------------------------------------------------------
// Kernel 1: reduce partials + gating MLP + top-2 + renormalize (all f32)
__global__ void gate_kernel(const float* __restrict__ partial,
                            const float* __restrict__ gw1, const float* __restrict__ gb1,
                            const float* __restrict__ gw2, const float* __restrict__ gb2,
                            int* __restrict__ ridx, float* __restrict__ rwgt) {
  const int b = blockIdx.x, j = threadIdx.x;
  __shared__ float pl[D_];
  __shared__ float hid[GH_];
  __shared__ float logits[E_];
  for (int d = j; d < D_; d += 256) {
    float s = 0.f;
    #pragma unroll
    for (int sb = 0; sb < 8; ++sb) s += partial[((size_t)b * 8 + sb) * D_ + d];
    pl[d] = s * (1.f / (float)S_);
  }
  __syncthreads();
  float acc = gb1[j];
  for (int d = 0; d < D_; ++d) acc += pl[d] * gw1[d * GH_ + j];
  hid[j] = fmaxf(acc, 0.f);
  __syncthreads();
  if (j < E_) {
    float l = gb2[j];
    for (int i = 0; i < GH_; ++i) l += hid[i] * gw2[i * E_ + j];
    logits[j] = l;
  }
  __syncthreads();
  if (j == 0) {
    int i0 = 0; float v0 = logits[0];
    for (int i = 1; i < E_; ++i) if (logits[i] > v0) { v0 = logits[i]; i0 = i; }
    int i1 = -1; float v1 = -3.0e38f;
    for (int i = 0; i < E_; ++i) {
      if (i == i0) continue;
      if (logits[i] > v1) { v1 = logits[i]; i1 = i; }
    }
    float r1 = expf(v1 - v0);
    float norm = 1.f + r1;
    ridx[b * 2 + 0] = i0;         ridx[b * 2 + 1] = i1;
    rwgt[b * 2 + 0] = 1.f / norm; rwgt[b * 2 + 1] = r1 / norm;
  }
}

// ---------------------------------------------------------------------------
// Kernel 2: stable counting-rank sort of pairs by expert id. 1 block, 128 thr.
__global__ void sort_pairs_kernel(const int* __restrict__ ridx, int* __restrict__ order) {
  __shared__ int se[NPAIR];
  const int t = threadIdx.x;
  se[t] = ridx[t];
  __syncthreads();
  const int e = se[t];
  int rank = 0;
  for (int j = 0; j < NPAIR; ++j) {
    const int ej = se[j];
    rank += (ej < e || (ej == e && j < t)) ? 1 : 0;
  }
  order[rank] = t;
}

// ---------------------------------------------------------------------------
// Kernel 3: token-stationary gathered GEMM + bias + ReLU + sum over s
//   A (w1t chunks) streams via async global_load_lds into a double-buffered
//   64-KiB LDS tile (512h x 64k, fragment order). B (tokens) lives in a
//   3-slot LDS slab ring (each slab 64 tok x 64 k bf16, read only in its own
//   K-step). 32 intervals (16 kkpair x 2 hh), ONE barrier each with counted
//   vmcnt (never 0 mid-loop) -> gather + next-DMA stay in flight.
// grid(1024), block 512 (8 waves); pairs sorted by expert + XCD-chunked.
__global__ __launch_bounds__(512, 2) void expert_kernel(
    const int* __restrict__ x, const float* __restrict__ exp_emb,
    const ushort* __restrict__ w1t, const float* __restrict__ exp_b1,
    const int* __restrict__ ridx, const int* __restrict__ order,
    float* __restrict__ p_part) {
  const int id     = blockIdx.x;           // 0..1023
  const int xcd    = id & 7;
  const int within = id >> 3;              // 0..127
  const int slot   = xcd * 128 + within;   // contiguous sorted chunk per XCD
  const int pr     = order[slot >> 3];
  const int sblk   = slot & 7;
  const int b      = pr >> 1;
  const int tid    = threadIdx.x;

  __shared__ __align__(16) ushort lA[2][32768];  // 2 x 64 KiB A tile (512h x 64k)
  __shared__ __align__(16) ushort lB[3][4096];   // 3 x 8 KiB B slab ring

  const int e = ridx[pr];

  // gather mapping: thread covers token row (tid>>3), 8 floats at (tid&7)*8
  const int grow = tid >> 3, gkq = (tid & 7) * 8;
  const int tok  = x[b * S_ + sblk * 64 + grow];
  const float* gptr = exp_emb + ((size_t)e * V_ + tok) * D_ + gkq;
  const int bwidx = grow * 64 + (gkq ^ ((grow & 7) << 3));   // swizzled ushort idx

  const int wid = tid >> 6, lane = tid & 63;
  const int l15 = lane & 15, l16 = lane >> 4;
  const int sw  = (l15 & 7) << 3;

  const char* aStream = (const char*)(w1t + (size_t)e * (32 * 32768));

  f32x4 acc[2][4][4];
  #pragma unroll
  for (int hh = 0; hh < 2; ++hh)
    #pragma unroll
    for (int i = 0; i < 4; ++i)
      #pragma unroll
      for (int j = 0; j < 4; ++j) acc[hh][i][j] = (f32x4){0.f, 0.f, 0.f, 0.f};

  f32x4 st[2][2];
  // ---- prologue: slabs 0,1 loaded+written; slab 2 loads in flight; DMA chunk 0
  st[0][0] = __builtin_nontemporal_load(reinterpret_cast<const f32x4*>(gptr));
  st[0][1] = __builtin_nontemporal_load(reinterpret_cast<const f32x4*>(gptr + 4));
  st[1][0] = __builtin_nontemporal_load(reinterpret_cast<const f32x4*>(gptr + 64));
  st[1][1] = __builtin_nontemporal_load(reinterpret_cast<const f32x4*>(gptr + 68));
  *reinterpret_cast<uint4*>(&lB[0][bwidx]) = cvt8(st[0][0], st[0][1]);
  *reinterpret_cast<uint4*>(&lB[1][bwidx]) = cvt8(st[1][0], st[1][1]);
  st[0][0] = __builtin_nontemporal_load(reinterpret_cast<const f32x4*>(gptr + 128));
  st[0][1] = __builtin_nontemporal_load(reinterpret_cast<const f32x4*>(gptr + 132));
  #pragma unroll
  for (int n = 0; n < 8; ++n)
    gload_lds16(aStream + n * 8192 + tid * 16,
                (char*)&lA[0][0] + n * 8192 + wid * 1024);
  asm volatile("s_waitcnt vmcnt(0) lgkmcnt(0)" ::: "memory");
  __builtin_amdgcn_s_barrier();

  // ---- main loop: 32 intervals, fully unrolled (static indices & waits)
  #pragma unroll
  for (int i = 0; i < 32; ++i) {
    const int cur = i & 1, r = i >> 1, slot3 = r % 3;
    // write B slab w = r+2 (st regs loaded ~2.5 intervals ago; the compiler's
    // own vmcnt wait here can only drain DMA(i) - needed this interval anyway)
    if ((i & 1) && (r + 2 < 16)) {
      const int w = r + 2;
      *reinterpret_cast<uint4*>(&lB[w % 3][bwidx]) = cvt8(st[w & 1][0], st[w & 1][1]);
    }
    // issue one gather load (slab s: load0 at i=2s-6, load1 at i=2s-5)
    if (!(i & 1)) {
      const int s = i / 2 + 3;
      if (s < 16) st[s & 1][0] = __builtin_nontemporal_load(
          reinterpret_cast<const f32x4*>(gptr + s * 64));
    } else {
      const int s = (i + 5) / 2;
      if (s < 16) st[s & 1][1] = __builtin_nontemporal_load(
          reinterpret_cast<const f32x4*>(gptr + s * 64 + 4));
    }
    // counted wait: ensures DMA(i) (issued last interval) is complete while
    // keeping this interval's gather load in flight; lgkm drains ds ops.
    if (i <= 25) asm volatile("s_waitcnt vmcnt(1) lgkmcnt(0)" ::: "memory");
    else         asm volatile("s_waitcnt vmcnt(0) lgkmcnt(0)" ::: "memory");
    __builtin_amdgcn_s_barrier();
    // async DMA of chunk i+1 into the other A buffer (overlaps MFMAs below)
    if (i < 31) {
      #pragma unroll
      for (int n = 0; n < 8; ++n)
        gload_lds16(aStream + (size_t)(i + 1) * 65536 + n * 8192 + tid * 16,
                    (char*)&lA[cur ^ 1][0] + n * 8192 + wid * 1024);
    }
    // MFMA phase: hh = i&1, kkpair = i>>1
    __builtin_amdgcn_s_setprio(1);
    #pragma unroll
    for (int ks = 0; ks < 2; ++ks) {
      bf16x8 af[4], bfr[4];
      #pragma unroll
      for (int fi = 0; fi < 4; ++fi)
        af[fi] = *reinterpret_cast<const bf16x8*>(
            (const char*)&lA[cur][0] + wid * 8192 + ks * 4096 + fi * 1024 + lane * 16);
      #pragma unroll
      for (int j = 0; j < 4; ++j)
        bfr[j] = *reinterpret_cast<const bf16x8*>(
            &lB[slot3][(j * 16 + l15) * 64 + ((ks * 32 + l16 * 8) ^ sw)]);
      #pragma unroll
      for (int fi = 0; fi < 4; ++fi)
        #pragma unroll
        for (int j = 0; j < 4; ++j)
          acc[cur][fi][j] =
              __builtin_amdgcn_mfma_f32_16x16x32_bf16(af[fi], bfr[j], acc[cur][fi][j], 0, 0, 0);
    }
    __builtin_amdgcn_s_setprio(0);
  }

  // ---- epilogue: + bias, ReLU, sum over 64 s columns, store partials
  float* outRow = p_part + (size_t)(sblk * NPAIR + pr) * H_;
  const float* biasE = exp_b1 + e * H_;
  #pragma unroll
  for (int hh = 0; hh < 2; ++hh) {
    #pragma unroll
    for (int i = 0; i < 4; ++i) {
      #pragma unroll
      for (int r = 0; r < 4; ++r) {
        const int h = hh * 512 + wid * 64 + i * 16 + l16 * 4 + r;
        const float bias = biasE[h];
        float v = 0.f;
        #pragma unroll
        for (int j = 0; j < 4; ++j) v += fmaxf(acc[hh][i][j][r] + bias, 0.f);
        #pragma unroll
        for (int m = 1; m < 16; m <<= 1) v += __shfl_xor(v, m);  // reduce 16 s-cols
        if (l15 == 0) outRow[h] = v;
      }
    }
  }
}

// ---------------------------------------------------------------------------
// Kernel 4: out[b][c] = sum_k rw * ( (sum_sb p_part)/S @ W2[e] + b2[e] )
__global__ void finalize_kernel(const float* __restrict__ p_part,
                                const int* __restrict__ ridx, const float* __restrict__ rwgt,
                                const float* __restrict__ w2, const float* __restrict__ b2,
                                float* __restrict__ out) {
  const int b = blockIdx.x, t = threadIdx.x;
  const int c = t & 15, g = t >> 4;
  __shared__ float red[16][17];
  float res = 0.f;
  for (int kk = 0; kk < 2; ++kk) {
    const int pr = b * 2 + kk;
    const int e = ridx[pr];
    const float w = rwgt[pr];
    float dot = 0.f;
    for (int h = g; h < H_; h += 16) {
      float pm = 0.f;
      #pragma unroll
      for (int sb = 0; sb < 8; ++sb) pm += p_part[(size_t)(sb * NPAIR + pr) * H_ + h];
      dot += pm * w2[((size_t)e * H_ + h) * C_ + c];
    }
    red[g][c] = dot;
    __syncthreads();
    if (g == 0) {
      float s = 0.f;
      #pragma unroll
      for (int i = 0; i < 16; ++i) s += red[i][c];
      res += w * (s * (1.f / (float)S_) + b2[e * C_ + c]);
    }
    __syncthreads();
  }
  if (g == 0) out[b * C_ + c] = res;
}

// ---------------------------------------------------------------------------
extern "C" void kernel_launch(void* const* d_in, const int* in_sizes, int n_in,
                              void* d_out, int out_size, void* d_ws, size_t ws_size,
                              hipStream_t stream) {
  const int*   x    = (const int*)  d_in[0];
  const float* emb  = (const float*)d_in[1];
  const float* gw1  = (const float*)d_in[2];
  const float* gb1  = (const float*)d_in[3];
  const float* gw2  = (const float*)d_in[4];
  const float* gb2  = (const float*)d_in[5];
  const float* eemb = (const float*)d_in[6];
  const float* ew1  = (const float*)d_in[7];
  const float* eb1  = (const float*)d_in[8];
  const float* ew2  = (const float*)d_in[9];
  const float* eb2  = (const float*)d_in[10];
  float* out = (float*)d_out;

  char* ws = (char*)d_ws;
  const size_t OFF_W1T   = 0;                            // 16 MiB
  const size_t OFF_PART  = (size_t)16 << 20;             // 2 MiB
  const size_t OFF_RIDX  = OFF_PART + ((size_t)2 << 20);
  const size_t OFF_RWGT  = OFF_RIDX + 1024;
  const size_t OFF_ORDER = OFF_RWGT + 1024;
  const size_t OFF_PPART = OFF_ORDER + 1024;             // 4 MiB

  ushort* w1t    = (ushort*)(ws + OFF_W1T);
  float*  part   = (float*) (ws + OFF_PART);
  int*    ridx   = (int*)   (ws + OFF_RIDX);
  float*  rwgt   = (float*) (ws + OFF_RWGT);
  int*    order  = (int*)   (ws + OFF_ORDER);
  float*  ppart  = (float*) (ws + OFF_PPART);

  prep_kernel<<<dim3(2560), 256, 0, stream>>>(ew1, w1t, x, emb, part);
  gate_kernel<<<dim3(B_), 256, 0, stream>>>(part, gw1, gb1, gw2, gb2, ridx, rwgt);
  sort_pairs_kernel<<<dim3(1), 128, 0, stream>>>(ridx, order);
  expert_kernel<<<dim3(1024), 512, 0, stream>>>(x, eemb, w1t, eb1, ridx, order, ppart);
  finalize_kernel<<<dim3(B_), 256, 0, stream>>>(ppart, ridx, rwgt, ew2, eb2, out);
}